// Round 2
// baseline (316.122 us; speedup 1.0000x reference)
//
#include <hip/hip_runtime.h>
#include <hip/hip_bf16.h>

// MoE ExpertGroup: T=2048 tokens, E=8 experts, D=1024, I=2048.
// Device dtypes per reference: x[T,D] f32, expert_indices[T] i32,
// w_gate[E,D,I] f32, w_up[E,D,I] f32, w_down[E,I,D] f32 ; out[T,D] f32.
// Compute: bf16 MFMA (fp32 has no MFMA on CDNA4); fp32->bf16 conversion is
// fused into LDS staging. Tolerance is 2%*max|ref| -> bf16-safe.
// Structure: token permutation by expert, then 2 grouped GEMMs.

#define T_ 2048
#define E_ 8
#define D_ 1024
#define I_ 2048
#define BM 64
#define BN 64
#define BK 64
#define MAXRT ((T_ / BM) + E_)  // 40 worst-case row tiles

typedef __attribute__((ext_vector_type(8))) __bf16 bf16x8;
typedef __attribute__((ext_vector_type(4))) float f32x4;
typedef __attribute__((ext_vector_type(4))) unsigned short us4;
typedef __attribute__((ext_vector_type(8))) unsigned short us8;

__device__ __forceinline__ unsigned short b16(float f) {
  __hip_bfloat16 h = __float2bfloat16(f);  // RNE
  return *reinterpret_cast<unsigned short*>(&h);
}

__device__ __forceinline__ void gload16(const void* g, unsigned lds_addr) {
  __builtin_amdgcn_global_load_lds(
      (const __attribute__((address_space(1))) unsigned int*)(unsigned long long)g,
      (__attribute__((address_space(3))) unsigned int*)(unsigned long long)lds_addr,
      16, 0, 0);
}

// ---------------- kernel 1: count + permute ----------------
// meta (ints): [0..7] counts, [8..15] segment starts, [16..16+T) perm
__global__ void moe_count(const int* __restrict__ eidx, int* __restrict__ meta) {
  __shared__ int cnt[E_], cur[E_];
  const int tid = threadIdx.x;
  if (tid < E_) cnt[tid] = 0;
  __syncthreads();
  for (int t = tid; t < T_; t += 256) atomicAdd(&cnt[eidx[t]], 1);
  __syncthreads();
  if (tid == 0) {
    int s = 0;
    for (int i = 0; i < E_; ++i) {
      int c = cnt[i];
      meta[i] = c;
      meta[8 + i] = s;
      cur[i] = s;
      s += c;
    }
  }
  __syncthreads();
  for (int t = tid; t < T_; t += 256) {
    int e = eidx[t];
    int pp = atomicAdd(&cur[e], 1);
    meta[16 + pp] = t;
  }
}

__device__ __forceinline__ bool resolve_tile(const int* __restrict__ meta, int rt,
                                             int& e, int& row0, int& rows_valid) {
  int cum = 0;
  e = -1;
  row0 = 0;
  rows_valid = 0;
#pragma unroll
  for (int i = 0; i < E_; ++i) {
    int n = meta[i];
    int nt = (n + BM - 1) >> 6;
    if (e < 0 && rt < cum + nt) {
      e = i;
      int segS = meta[8 + i];
      row0 = segS + (rt - cum) * BM;
      int rv = segS + n - row0;
      rows_valid = rv > BM ? BM : rv;
    }
    cum += nt;
  }
  return e >= 0;
}

// LDS tile layouts (per K-tile, bf16):
//  A  [64 m][8 chunks]  : row m*128B, chunk c holds k-block (c ^ (m&7)), 8 k each
//  BT [64 n][8 chunks]  : row n*128B, chunk c holds k-block (c ^ (n&7))  (B transposed)
// Fragments (mfma 16x16x32): lane l=(p=l&15, h=l>>4):
//  A[m=mf*16+p][k=kk*32+h*8+j] -> b128 @ (mf*16+p)*128 + ((kk*4+h)^(p&7))*16
//  B[k][n=wv*16+p]             -> b128 @ (wv*16+p)*128 + ((kk*4+h)^(p&7))*16

// ---------------- kernel 2: gate/up GEMM + SiLU ----------------
// buffer: A @ +0 (8K), BTgate @ +8K, BTup @ +16K; double buffered (48K)
__global__ __launch_bounds__(256) void moe_gemm1(
    const float* __restrict__ x, const float* __restrict__ wg,
    const float* __restrict__ wu, const int* __restrict__ meta,
    __hip_bfloat16* __restrict__ hidden) {
  extern __shared__ char smem[];
  const int tid = threadIdx.x;
  const int lane = tid & 63;
  const int wv = tid >> 6;
  const int p = lane & 15, h = lane >> 4;

  int e, row0, rows_valid;
  if (!resolve_tile(meta, blockIdx.x, e, row0, rows_valid)) return;
  const int ct = blockIdx.y;
  const int* __restrict__ perm = meta + 16;

  // A staging: 2 slots/thread, slot s = q*256+tid -> (m=s>>3, kb=s&7), 8 fp32 along k
  const float* xp[2];
  unsigned lwA[2];
#pragma unroll
  for (int q = 0; q < 2; ++q) {
    const int s = q * 256 + tid;
    const int m = s >> 3, kb = s & 7;
    const int mm = m < rows_valid ? m : (rows_valid - 1);
    const int tok = perm[row0 + mm];
    xp[q] = x + (size_t)tok * D_ + kb * 8;
    lwA[q] = (unsigned)(m * 128 + ((kb ^ (m & 7)) * 16));
  }
  // B staging: 4 slots/thread, slot (n=lane, kg=q*4+wv), 4 fp32 along k (stride I_)
  const float* wgp = wg + (size_t)e * D_ * I_ + (size_t)(ct * BN + lane);
  const float* wup = wu + (size_t)e * D_ * I_ + (size_t)(ct * BN + lane);
  unsigned lwB[4];
#pragma unroll
  for (int q = 0; q < 4; ++q) {
    const int kg = q * 4 + wv;
    lwB[q] = (unsigned)(lane * 128 + (((kg >> 1) ^ (lane & 7)) * 16) + (kg & 1) * 8);
  }

  unsigned offA[4][2], offB[2];
#pragma unroll
  for (int mf = 0; mf < 4; ++mf)
#pragma unroll
    for (int kk = 0; kk < 2; ++kk)
      offA[mf][kk] = (unsigned)((mf * 16 + p) * 128 + (((kk * 4 + h) ^ (p & 7)) * 16));
#pragma unroll
  for (int kk = 0; kk < 2; ++kk)
    offB[kk] = (unsigned)((wv * 16 + p) * 128 + (((kk * 4 + h) ^ (p & 7)) * 16));

  f32x4 accG[4], accU[4];
#pragma unroll
  for (int i = 0; i < 4; ++i) {
    accG[i] = f32x4{0.f, 0.f, 0.f, 0.f};
    accU[i] = f32x4{0.f, 0.f, 0.f, 0.f};
  }

  float4 ra[2], rb[2];
  float rg[4][4], ru[4][4];
  auto LOADT = [&](int kt) {
#pragma unroll
    for (int q = 0; q < 2; ++q) {
      ra[q] = *(const float4*)(xp[q] + kt * BK);
      rb[q] = *(const float4*)(xp[q] + kt * BK + 4);
    }
#pragma unroll
    for (int q = 0; q < 4; ++q) {
      const int kg = q * 4 + wv;
#pragma unroll
      for (int j = 0; j < 4; ++j) {
        const size_t ko = (size_t)(kt * BK + kg * 4 + j) * I_;
        rg[q][j] = wgp[ko];
        ru[q][j] = wup[ko];
      }
    }
  };
  auto WRITET = [&](unsigned base) {
#pragma unroll
    for (int q = 0; q < 2; ++q) {
      us8 v = {b16(ra[q].x), b16(ra[q].y), b16(ra[q].z), b16(ra[q].w),
               b16(rb[q].x), b16(rb[q].y), b16(rb[q].z), b16(rb[q].w)};
      *(us8*)(smem + base + lwA[q]) = v;
    }
#pragma unroll
    for (int q = 0; q < 4; ++q) {
      us4 vg = {b16(rg[q][0]), b16(rg[q][1]), b16(rg[q][2]), b16(rg[q][3])};
      us4 vu = {b16(ru[q][0]), b16(ru[q][1]), b16(ru[q][2]), b16(ru[q][3])};
      *(us4*)(smem + base + 8192u + lwB[q]) = vg;
      *(us4*)(smem + base + 16384u + lwB[q]) = vu;
    }
  };

  LOADT(0);
  WRITET(0);
  __syncthreads();
  const int KT = D_ / BK;  // 16
  for (int kt = 0; kt < KT; ++kt) {
    const unsigned cur = (unsigned)(kt & 1) * 24576u;
    if (kt + 1 < KT) LOADT(kt + 1);
#pragma unroll
    for (int kk = 0; kk < 2; ++kk) {
      bf16x8 aF[4];
#pragma unroll
      for (int mf = 0; mf < 4; ++mf)
        aF[mf] = *(const bf16x8*)(smem + cur + offA[mf][kk]);
      const bf16x8 bG = *(const bf16x8*)(smem + cur + 8192u + offB[kk]);
      const bf16x8 bU = *(const bf16x8*)(smem + cur + 16384u + offB[kk]);
#pragma unroll
      for (int mf = 0; mf < 4; ++mf) {
        accG[mf] = __builtin_amdgcn_mfma_f32_16x16x32_bf16(aF[mf], bG, accG[mf], 0, 0, 0);
        accU[mf] = __builtin_amdgcn_mfma_f32_16x16x32_bf16(aF[mf], bU, accU[mf], 0, 0, 0);
      }
    }
    if (kt + 1 < KT) WRITET(cur ^ 24576u);
    __syncthreads();
  }

  // epilogue: C/D layout col=lane&15, row=(lane>>4)*4+j
  const int cbase = ct * BN + wv * 16 + p;
#pragma unroll
  for (int mf = 0; mf < 4; ++mf) {
#pragma unroll
    for (int j = 0; j < 4; ++j) {
      const int r = mf * 16 + h * 4 + j;
      if (r < rows_valid) {
        const float gv = accG[mf][j], uv = accU[mf][j];
        const float hv = gv / (1.f + __expf(-gv)) * uv;
        hidden[(size_t)(row0 + r) * I_ + cbase] = __float2bfloat16(hv);
      }
    }
  }
}

// ---------------- kernel 3: down GEMM + scatter ----------------
// buffer: A @ +0 (8K, bf16 hidden via global_load_lds w/ pre-swizzled src),
//         BT @ +8K (wdown fp32 -> bf16 reg-staged); double buffered (32K)
__global__ __launch_bounds__(256) void moe_gemm2(
    const __hip_bfloat16* __restrict__ hidden, const float* __restrict__ wd,
    const int* __restrict__ meta, float* __restrict__ out) {
  extern __shared__ char smem[];
  const int tid = threadIdx.x;
  const int lane = tid & 63;
  const int wv = tid >> 6;
  const int p = lane & 15, h = lane >> 4;

  int e, row0, rows_valid;
  if (!resolve_tile(meta, blockIdx.x, e, row0, rows_valid)) return;
  const int ct = blockIdx.y;
  const int* __restrict__ perm = meta + 16;

  // A: global_load_lds, dest = slot*16 (linear); source pre-swizzled so that
  // phys chunk pcb holds k-block (pcb ^ (m&7))  [m173 pattern]
  size_t gAoff[2];
  unsigned lA[2];
#pragma unroll
  for (int q = 0; q < 2; ++q) {
    const int s = (wv + q * 4) * 64 + lane;
    const int m = s >> 3, pcb = s & 7;
    const int kblk = pcb ^ (m & 7);
    int mm = row0 + m;
    if (mm > T_ - 1) mm = T_ - 1;  // padded rows: clamp (discarded later)
    gAoff[q] = (size_t)mm * I_ + kblk * 8;
    lA[q] = (unsigned)(s * 16);
  }
  const float* wdp = wd + (size_t)e * I_ * D_ + (size_t)(ct * BN + lane);
  unsigned lwB[4];
#pragma unroll
  for (int q = 0; q < 4; ++q) {
    const int kg = q * 4 + wv;
    lwB[q] = (unsigned)(lane * 128 + (((kg >> 1) ^ (lane & 7)) * 16) + (kg & 1) * 8);
  }

  unsigned offA[4][2], offB[2];
#pragma unroll
  for (int mf = 0; mf < 4; ++mf)
#pragma unroll
    for (int kk = 0; kk < 2; ++kk)
      offA[mf][kk] = (unsigned)((mf * 16 + p) * 128 + (((kk * 4 + h) ^ (p & 7)) * 16));
#pragma unroll
  for (int kk = 0; kk < 2; ++kk)
    offB[kk] = (unsigned)((wv * 16 + p) * 128 + (((kk * 4 + h) ^ (p & 7)) * 16));

  f32x4 acc[4];
#pragma unroll
  for (int i = 0; i < 4; ++i) acc[i] = f32x4{0.f, 0.f, 0.f, 0.f};

  float rd[4][4];
  auto GLOADA = [&](unsigned base, int kt) {
#pragma unroll
    for (int q = 0; q < 2; ++q)
      gload16(hidden + gAoff[q] + kt * BK,
              (unsigned)(unsigned long long)(smem + base) + lA[q]);
  };
  auto LOADB = [&](int kt) {
#pragma unroll
    for (int q = 0; q < 4; ++q) {
      const int kg = q * 4 + wv;
#pragma unroll
      for (int j = 0; j < 4; ++j)
        rd[q][j] = wdp[(size_t)(kt * BK + kg * 4 + j) * D_];
    }
  };
  auto WRITEB = [&](unsigned base) {
#pragma unroll
    for (int q = 0; q < 4; ++q) {
      us4 v = {b16(rd[q][0]), b16(rd[q][1]), b16(rd[q][2]), b16(rd[q][3])};
      *(us4*)(smem + base + 8192u + lwB[q]) = v;
    }
  };

  GLOADA(0, 0);
  LOADB(0);
  WRITEB(0);
  __syncthreads();  // drains vmcnt (global_load_lds) + lgkmcnt
  const int KT = I_ / BK;  // 32
  for (int kt = 0; kt < KT; ++kt) {
    const unsigned cur = (unsigned)(kt & 1) * 16384u;
    if (kt + 1 < KT) {
      GLOADA(cur ^ 16384u, kt + 1);
      LOADB(kt + 1);
    }
#pragma unroll
    for (int kk = 0; kk < 2; ++kk) {
      bf16x8 aF[4];
#pragma unroll
      for (int mf = 0; mf < 4; ++mf)
        aF[mf] = *(const bf16x8*)(smem + cur + offA[mf][kk]);
      const bf16x8 bB = *(const bf16x8*)(smem + cur + 8192u + offB[kk]);
#pragma unroll
      for (int mf = 0; mf < 4; ++mf)
        acc[mf] = __builtin_amdgcn_mfma_f32_16x16x32_bf16(aF[mf], bB, acc[mf], 0, 0, 0);
    }
    if (kt + 1 < KT) WRITEB(cur ^ 16384u);
    __syncthreads();
  }

  const int cbase = ct * BN + wv * 16 + p;
#pragma unroll
  for (int mf = 0; mf < 4; ++mf) {
#pragma unroll
    for (int j = 0; j < 4; ++j) {
      const int r = mf * 16 + h * 4 + j;
      if (r < rows_valid) {
        const int tok = perm[row0 + r];
        out[(size_t)tok * D_ + cbase] = acc[mf][j];
      }
    }
  }
}

extern "C" void kernel_launch(void* const* d_in, const int* in_sizes, int n_in,
                              void* d_out, int out_size, void* d_ws, size_t ws_size,
                              hipStream_t stream) {
  const float* x = (const float*)d_in[0];
  const int* eidx = (const int*)d_in[1];
  const float* wgate = (const float*)d_in[2];
  const float* wup = (const float*)d_in[3];
  const float* wdown = (const float*)d_in[4];
  float* out = (float*)d_out;

  int* meta = (int*)d_ws;                                           // 8.3 KB used
  __hip_bfloat16* hidden = (__hip_bfloat16*)((char*)d_ws + 65536);  // T*I*2 = 8 MB

  moe_count<<<dim3(1), dim3(256), 0, stream>>>(eidx, meta);
  moe_gemm1<<<dim3(MAXRT, I_ / BN), dim3(256), 48 * 1024, stream>>>(x, wgate, wup, meta, hidden);
  moe_gemm2<<<dim3(MAXRT, D_ / BN), dim3(256), 32 * 1024, stream>>>(hidden, wdown, meta, out);
}